// Round 6
// baseline (350.973 us; speedup 1.0000x reference)
//
#include <hip/hip_runtime.h>
#include <hip/hip_cooperative_groups.h>
#include <math.h>

namespace cg = cooperative_groups;

// ModifiedBarlowTwinsLoss — augmented-Gram, bf16 MFMA, ONE cooperative kernel.
// Phases (grid.sync between): P0 convT+MT+zero, P1 gram, P2 gsum (many-block
// fold, R3-proven), P3 stats+hist, P4 term. Bodies are the R3 (118.3us) ones.
// loss = (1/D^2) sum Ga~ Gb~ - (2/D) sum_c Sa~·Sb~ + sum_c n_c^2

#define NN 8192
#define DD 512
#define NC 100
#define SPLITK 16
#define NXT 10            // X^T X upper-triangle tiles
#define NTILE 14          // + 4 X^T M tiles
#define GRID 448

// ws byte offsets
#define GA_B    0u           // 512*512*4
#define GB_B    1048576u
#define RTA_B   2097152u     // RT: [128 classes][512 cols] f32
#define RTB_B   2359296u
#define MUA_B   2621440u
#define MUB_B   2623488u
#define RSA_B   2625536u
#define RSB_B   2627584u
#define CNT_B   2629632u
#define XTA_B   4194304u     // 512*8192*2
#define XTB_B   12582912u
#define MT_B    20971520u    // 128*8192*2
#define PART_B  23068672u    // 2*14*16*16384*4 (end ~52.4 MB)

typedef __attribute__((ext_vector_type(8))) short short8;
typedef __attribute__((ext_vector_type(4))) float f32x4;

__constant__ int c_ti[NTILE] = {0,0,0,0,1,1,1,2,2,3, 0,1,2,3};
__constant__ int c_tj[NTILE] = {0,1,2,3,1,2,3,2,3,3, 4,4,4,4};
__constant__ float c_w[NXT]  = {1.f,2.f,2.f,2.f,1.f,2.f,2.f,1.f,2.f,1.f};

#if defined(__has_builtin)
#if __has_builtin(__builtin_amdgcn_global_load_lds)
#define HAVE_GLL 1
#endif
#endif

#ifdef HAVE_GLL
__device__ __forceinline__ void async16(const void* g, void* l) {
    __builtin_amdgcn_global_load_lds(
        (const __attribute__((address_space(1))) void*)g,
        (__attribute__((address_space(3))) void*)l, 16, 0, 0);
}
#endif

__device__ __forceinline__ unsigned short f2bf_rne(float f) {
    unsigned int u = __builtin_bit_cast(unsigned int, f);
    u += 0x7fffu + ((u >> 16) & 1u);
    return (unsigned short)(u >> 16);
}

__device__ __forceinline__ float block_reduce_sum(float v) {
    __shared__ float red[8];
    int lane = threadIdx.x & 63;
    int wave = threadIdx.x >> 6;
    #pragma unroll
    for (int off = 32; off > 0; off >>= 1) v += __shfl_down(v, off, 64);
    if (lane == 0) red[wave] = v;
    __syncthreads();
    float s = 0.f;
    if (threadIdx.x == 0) {
        int nw = (blockDim.x + 63) >> 6;
        for (int w = 0; w < nw; w++) s += red[w];
    }
    return s; // thread 0 only
}

__global__ __launch_bounds__(256, 2) void k_fused(
        const float* __restrict__ A, const float* __restrict__ B,
        const int* __restrict__ labels,
        short* __restrict__ XTa, short* __restrict__ XTb, short* __restrict__ MT,
        float* __restrict__ part,
        float* __restrict__ Ga, float* __restrict__ Gb,
        float* __restrict__ RTa, float* __restrict__ RTb,
        float* __restrict__ mu_a, float* __restrict__ mu_b,
        float* __restrict__ rs_a, float* __restrict__ rs_b,
        int* __restrict__ counts, float* __restrict__ out) {
    cg::grid_group grid = cg::this_grid();
    __shared__ short LT[64][72];
    __shared__ short LA[128 * 64];
    __shared__ short LB[128 * 64];

    const int bid = blockIdx.x;
    const int t = threadIdx.x;

    // ---------------- P0: transpose-convert + one-hot MT + zero out --------
    for (int job = bid; job < 2177; job += GRID) {
        if (job < 2048) {
            int mat = job >> 10;
            const float* X = mat ? B : A;
            short* XT = mat ? XTb : XTa;
            int rem = job & 1023;
            int c0 = (rem >> 7) << 6;
            int k0 = (rem & 127) << 6;
            int cc = t & 15;
            int kb = t >> 4;
            #pragma unroll
            for (int s = 0; s < 4; s++) {
                int kr = kb + s * 16;
                float4 v = *(const float4*)&X[(size_t)(k0 + kr) * DD + c0 + cc * 4];
                LT[cc * 4 + 0][kr] = (short)f2bf_rne(v.x);
                LT[cc * 4 + 1][kr] = (short)f2bf_rne(v.y);
                LT[cc * 4 + 2][kr] = (short)f2bf_rne(v.z);
                LT[cc * 4 + 3][kr] = (short)f2bf_rne(v.w);
            }
            __syncthreads();
            #pragma unroll
            for (int s = 0; s < 2; s++) {
                int idx = s * 256 + t;
                int orow = idx >> 3;
                int och = idx & 7;
                *(uint4*)&XT[(size_t)(c0 + orow) * NN + k0 + och * 8] =
                    *(const uint4*)&LT[orow][och * 8];
            }
            __syncthreads();   // LT reused next job iteration
        } else if (job < 2176) {
            int c = job - 2048;
            unsigned short one = 0x3F80; // bf16 1.0
            ushort4* dst = (ushort4*)(MT + (size_t)c * NN);
            const int4* lb4 = (const int4*)labels;
            #pragma unroll
            for (int j = 0; j < 8; j++) {
                int i4 = j * 256 + t;
                int4 lb = lb4[i4];
                ushort4 v;
                v.x = (lb.x == c) ? one : (unsigned short)0;
                v.y = (lb.y == c) ? one : (unsigned short)0;
                v.z = (lb.z == c) ? one : (unsigned short)0;
                v.w = (lb.w == c) ? one : (unsigned short)0;
                dst[i4] = v;
            }
        } else {
            if (t == 0) out[0] = 0.f;
        }
    }
    grid.sync();

    // ---------------- P1: bf16 MFMA augmented Gram (448 jobs, 1:1) ---------
    {
        int mat = bid / (NTILE * SPLITK);
        int r = bid % (NTILE * SPLITK);
        int chunk = r / NTILE;
        int tile = r % NTILE;
        const short* XT = mat ? XTb : XTa;
        int ti = c_ti[tile], tj = c_tj[tile];
        const short* PA = XT + (size_t)ti * 128 * NN;
        const short* PB = (tj < 4) ? (XT + (size_t)tj * 128 * NN) : MT;
        int k0 = chunk * (NN / SPLITK);

        int wave = t >> 6, lane = t & 63;
        int quad = lane >> 4, l16 = lane & 15;
        int x7 = l16 & 7;
        int wrow = (wave >> 1) * 64, wcol = (wave & 1) * 64;

        int srow = lane >> 3;                 // row within 8-row segment
        int sc = (lane & 7) ^ srow;           // swizzled 16B-chunk index

        f32x4 acc[4][4];
        #pragma unroll
        for (int i = 0; i < 4; i++)
            #pragma unroll
            for (int j = 0; j < 4; j++) acc[i][j] = (f32x4)0.f;

        for (int kk = 0; kk < NN / SPLITK; kk += 64) {
            __syncthreads();
            #pragma unroll
            for (int rr = 0; rr < 4; rr++) {
                int seg = wave * 4 + rr;
                int row = seg * 8 + srow;
                const short* ga = PA + (size_t)row * NN + k0 + kk + sc * 8;
                const short* gb = PB + (size_t)row * NN + k0 + kk + sc * 8;
#ifdef HAVE_GLL
                async16(ga, &LA[seg * 512]);
                async16(gb, &LB[seg * 512]);
#else
                uint4 va = *(const uint4*)ga;
                uint4 vb = *(const uint4*)gb;
                *(uint4*)&LA[seg * 512 + lane * 8] = va;
                *(uint4*)&LB[seg * 512 + lane * 8] = vb;
#endif
            }
            __syncthreads();
            #pragma unroll
            for (int ks = 0; ks < 2; ks++) {
                short8 a[4], b[4];
                #pragma unroll
                for (int mt = 0; mt < 4; mt++)
                    a[mt] = *(const short8*)&LA[(wrow + mt * 16 + l16) * 64 +
                                                (((ks * 4 + quad) ^ x7) << 3)];
                #pragma unroll
                for (int nt = 0; nt < 4; nt++)
                    b[nt] = *(const short8*)&LB[(wcol + nt * 16 + l16) * 64 +
                                                (((ks * 4 + quad) ^ x7) << 3)];
                #pragma unroll
                for (int mt = 0; mt < 4; mt++)
                    #pragma unroll
                    for (int nt = 0; nt < 4; nt++)
                        acc[mt][nt] = __builtin_amdgcn_mfma_f32_16x16x32_bf16(
                            a[mt], b[nt], acc[mt][nt], 0, 0, 0);
            }
        }

        float* pbase = part + ((size_t)(mat * NTILE + tile) * SPLITK + chunk) * 16384;
        #pragma unroll
        for (int mt = 0; mt < 4; mt++)
            #pragma unroll
            for (int nt = 0; nt < 4; nt++)
                #pragma unroll
                for (int rj = 0; rj < 4; rj++) {
                    int rr2 = wrow + mt * 16 + quad * 4 + rj;
                    int cc2 = wcol + nt * 16 + l16;
                    pbase[rr2 * 128 + cc2] = acc[mt][nt][rj];
                }
    }
    grid.sync();

    // ---------------- P2: many-block split-K fold (R3 gsum) ----------------
    for (int job = bid; job < 2 * NTILE * 64; job += GRID) {
        int mat = job / (NTILE * 64);
        int rr = job % (NTILE * 64);
        int tile = rr / 64;
        int e = (rr % 64) * 256 + t;
        const float* p = part + (size_t)(mat * NTILE + tile) * SPLITK * 16384 + e;
        float s = 0.f;
        #pragma unroll
        for (int c = 0; c < SPLITK; c++) s += p[(size_t)c * 16384];
        int rw = e >> 7, cl = e & 127;
        if (tile < NXT) {
            float* G = mat ? Gb : Ga;
            G[(c_ti[tile] * 128 + rw) * DD + c_tj[tile] * 128 + cl] = s;
        } else {
            float* RT = mat ? RTb : RTa;
            RT[cl * DD + (tile - NXT) * 128 + rw] = s;   // [class][col]
        }
    }
    grid.sync();

    // ---------------- P3: stats + histogram --------------------------------
    if (bid < 3) {
        if (bid == 2) {
            __shared__ int h[NC];
            if (t < NC) h[t] = 0;
            __syncthreads();
            for (int i = t; i < NN; i += 256) atomicAdd(&h[labels[i]], 1);
            __syncthreads();
            if (t < NC) counts[t] = h[t];
        } else {
            int mat = bid;
            const float* RT = mat ? RTb : RTa;
            const float* G = mat ? Gb : Ga;
            for (int k = t; k < DD; k += 256) {
                float s = 0.f;
                for (int c = 0; c < 128; c++) s += RT[c * DD + k];
                float mu = s / (float)NN;
                float sumsq = G[k * DD + k];
                float var = (sumsq - (float)NN * mu * mu) / (float)(NN - 1);
                (mat ? mu_b : mu_a)[k] = mu;
                (mat ? rs_b : rs_a)[k] = rsqrtf(var);
            }
        }
    }
    grid.sync();

    // ---------------- P4: terms --------------------------------------------
    if (bid < 256) {
        float local = 0.f;
        for (int x = bid * 256 + t; x < DD * DD; x += 256 * 256) {
            int k = x >> 9, l = x & (DD - 1);
            if (l < k) continue;
            float w = (l == k) ? 1.f : 2.f;
            float ga = rs_a[k] * rs_a[l] * (Ga[x] - (float)NN * mu_a[k] * mu_a[l]);
            float gb = rs_b[k] * rs_b[l] * (Gb[x] - (float)NN * mu_b[k] * mu_b[l]);
            local += w * ga * gb;
        }
        float s = block_reduce_sum(local);
        if (t == 0) atomicAdd(out, s * (1.0f / ((float)DD * (float)DD)));
    } else if (bid < 256 + NC) {
        int c = bid - 256;
        float n = (float)counts[c];
        float local = 0.f;
        for (int k = t; k < DD; k += 256) {
            float ta = rs_a[k] * (RTa[c * DD + k] - n * mu_a[k]);
            float tb = rs_b[k] * (RTb[c * DD + k] - n * mu_b[k]);
            local += ta * tb;
        }
        float s = block_reduce_sum(local);
        if (t == 0) {
            float add = s * (-2.0f / (float)DD);
            if (c == 0) {
                float t3 = 0.f;
                for (int cc = 0; cc < NC; cc++) {
                    float nc = (float)counts[cc];
                    t3 += nc * nc;
                }
                add += t3;
            }
            atomicAdd(out, add);
        }
    }
}

extern "C" void kernel_launch(void* const* d_in, const int* in_sizes, int n_in,
                              void* d_out, int out_size, void* d_ws, size_t ws_size,
                              hipStream_t stream) {
    const float* z_a = (const float*)d_in[0];
    const float* z_b = (const float*)d_in[1];
    const int* labels = (const int*)d_in[2];
    float* out = (float*)d_out;
    char* wsb = (char*)d_ws;

    float* Ga = (float*)(wsb + GA_B);
    float* Gb = (float*)(wsb + GB_B);
    float* RTa = (float*)(wsb + RTA_B);
    float* RTb = (float*)(wsb + RTB_B);
    float* mu_a = (float*)(wsb + MUA_B);
    float* mu_b = (float*)(wsb + MUB_B);
    float* rs_a = (float*)(wsb + RSA_B);
    float* rs_b = (float*)(wsb + RSB_B);
    int* counts = (int*)(wsb + CNT_B);
    short* XTa = (short*)(wsb + XTA_B);
    short* XTb = (short*)(wsb + XTB_B);
    short* MT = (short*)(wsb + MT_B);
    float* part = (float*)(wsb + PART_B);

    void* kargs[] = {
        (void*)&z_a, (void*)&z_b, (void*)&labels,
        (void*)&XTa, (void*)&XTb, (void*)&MT, (void*)&part,
        (void*)&Ga, (void*)&Gb, (void*)&RTa, (void*)&RTb,
        (void*)&mu_a, (void*)&mu_b, (void*)&rs_a, (void*)&rs_b,
        (void*)&counts, (void*)&out
    };
    hipLaunchCooperativeKernel((void*)k_fused, dim3(GRID), dim3(256),
                               kargs, 0, stream);
}

// Round 7
// 131.509 us; speedup vs baseline: 2.6688x; 2.6688x over previous
//
#include <hip/hip_runtime.h>
#include <math.h>

// ModifiedBarlowTwinsLoss — augmented-Gram, bf16 MFMA, 4 launches (R3 bodies).
// Y = [X | M] (M = one-hot labels, 128 padded classes). MFMA pass gives:
//   X^T X (10 upper 128x128 tiles) -> Gram for term1
//   X^T M (4 tiles)                -> per-class column sums R (term2)
// mu/var exact fp32 from convT column partial sums (sum + sumsq).
// loss = (1/D^2) sum Ga~ Gb~ - (2/D) sum_c Sa~·Sb~ + sum_c n_c^2

#define NN 8192
#define DD 512
#define NC 100
#define SPLITK 16
#define NXT 10            // X^T X upper-triangle tiles
#define NTILE 14          // + 4 X^T M tiles

// ws byte offsets
#define GA_B    0u           // 512*512*4
#define GB_B    1048576u
#define RTA_B   2097152u     // RT: [128 classes][512 cols] f32
#define RTB_B   2359296u
#define MUA_B   2621440u
#define MUB_B   2623488u
#define RSA_B   2625536u
#define RSB_B   2627584u
#define CNT_B   2629632u
#define CPS_B   2630656u     // col partial sums  [2][8][128][64] f32 = 512 KB
#define CPQ_B   3154944u     // col partial sumsq [2][8][128][64] f32 = 512 KB
#define XTA_B   4194304u     // 512*8192*2
#define XTB_B   12582912u
#define MT_B    20971520u    // 128*8192*2
#define PART_B  23068672u    // 2*14*16*16384*4 (end ~52.4 MB)

typedef __attribute__((ext_vector_type(8))) short short8;
typedef __attribute__((ext_vector_type(4))) float f32x4;

__constant__ int c_ti[NTILE] = {0,0,0,0,1,1,1,2,2,3, 0,1,2,3};
__constant__ int c_tj[NTILE] = {0,1,2,3,1,2,3,2,3,3, 4,4,4,4};

#if defined(__has_builtin)
#if __has_builtin(__builtin_amdgcn_global_load_lds)
#define HAVE_GLL 1
#endif
#endif

#ifdef HAVE_GLL
__device__ __forceinline__ void async16(const void* g, void* l) {
    __builtin_amdgcn_global_load_lds(
        (const __attribute__((address_space(1))) void*)g,
        (__attribute__((address_space(3))) void*)l, 16, 0, 0);
}
#endif

__device__ __forceinline__ unsigned short f2bf_rne(float f) {
    unsigned int u = __builtin_bit_cast(unsigned int, f);
    u += 0x7fffu + ((u >> 16) & 1u);
    return (unsigned short)(u >> 16);
}

__device__ __forceinline__ float block_reduce_sum(float v) {
    __shared__ float red[8];
    int lane = threadIdx.x & 63;
    int wave = threadIdx.x >> 6;
    #pragma unroll
    for (int off = 32; off > 0; off >>= 1) v += __shfl_down(v, off, 64);
    if (lane == 0) red[wave] = v;
    __syncthreads();
    float s = 0.f;
    if (threadIdx.x == 0) {
        int nw = (blockDim.x + 63) >> 6;
        for (int w = 0; w < nw; w++) s += red[w];
    }
    return s; // thread 0 only
}

// L1: blocks 0..2047: fp32->bf16 transpose-convert (R3 body) + exact fp32
//     column sum/sumsq partials. Blocks 2048..2175: one-hot MT rows.
__global__ __launch_bounds__(256) void k_convT(const float* __restrict__ A,
                                               const float* __restrict__ B,
                                               const int* __restrict__ labels,
                                               short* __restrict__ XTa,
                                               short* __restrict__ XTb,
                                               short* __restrict__ MT,
                                               float* __restrict__ cps,
                                               float* __restrict__ cpq) {
    int bid = blockIdx.x;
    int t = threadIdx.x;

    if (bid >= 2048) {  // one-hot MT row
        int c = bid - 2048;
        unsigned short one = 0x3F80; // bf16 1.0
        ushort4* dst = (ushort4*)(MT + (size_t)c * NN);
        const int4* lb4 = (const int4*)labels;
        #pragma unroll
        for (int j = 0; j < 8; j++) {
            int i4 = j * 256 + t;
            int4 lb = lb4[i4];
            ushort4 v;
            v.x = (lb.x == c) ? one : (unsigned short)0;
            v.y = (lb.y == c) ? one : (unsigned short)0;
            v.z = (lb.z == c) ? one : (unsigned short)0;
            v.w = (lb.w == c) ? one : (unsigned short)0;
            dst[i4] = v;
        }
        return;
    }

    __shared__ short LT[64][72];
    __shared__ float cs[64], cq[64];
    int mat = bid >> 10;
    const float* X = mat ? B : A;
    short* XT = mat ? XTb : XTa;
    int rem = bid & 1023;
    int cgrp = rem >> 7;         // 0..7
    int kgrp = rem & 127;        // 0..127
    int c0 = cgrp << 6;
    int k0 = kgrp << 6;

    if (t < 64) { cs[t] = 0.f; cq[t] = 0.f; }

    int cc = t & 15;
    int kb = t >> 4;
    float a0 = 0.f, a1 = 0.f, a2 = 0.f, a3 = 0.f;
    float q0 = 0.f, q1 = 0.f, q2 = 0.f, q3 = 0.f;
    #pragma unroll
    for (int s = 0; s < 4; s++) {
        int kr = kb + s * 16;
        float4 v = *(const float4*)&X[(size_t)(k0 + kr) * DD + c0 + cc * 4];
        a0 += v.x; a1 += v.y; a2 += v.z; a3 += v.w;
        q0 += v.x * v.x; q1 += v.y * v.y; q2 += v.z * v.z; q3 += v.w * v.w;
        LT[cc * 4 + 0][kr] = (short)f2bf_rne(v.x);
        LT[cc * 4 + 1][kr] = (short)f2bf_rne(v.y);
        LT[cc * 4 + 2][kr] = (short)f2bf_rne(v.z);
        LT[cc * 4 + 3][kr] = (short)f2bf_rne(v.w);
    }
    __syncthreads();
    #pragma unroll
    for (int s = 0; s < 2; s++) {
        int idx = s * 256 + t;
        int orow = idx >> 3;
        int och = idx & 7;
        *(uint4*)&XT[(size_t)(c0 + orow) * NN + k0 + och * 8] =
            *(const uint4*)&LT[orow][och * 8];
    }
    atomicAdd(&cs[cc * 4 + 0], a0); atomicAdd(&cq[cc * 4 + 0], q0);
    atomicAdd(&cs[cc * 4 + 1], a1); atomicAdd(&cq[cc * 4 + 1], q1);
    atomicAdd(&cs[cc * 4 + 2], a2); atomicAdd(&cq[cc * 4 + 2], q2);
    atomicAdd(&cs[cc * 4 + 3], a3); atomicAdd(&cq[cc * 4 + 3], q3);
    __syncthreads();
    if (t < 64) {
        size_t slot = ((size_t)(mat * 8 + cgrp) * 128 + kgrp) * 64 + t;
        cps[slot] = cs[t];
        cpq[slot] = cq[t];
    }
}

// L2: blocks 0..447: bf16 MFMA augmented Gram (R3 body);
//     block 448: histogram + zero out; blocks 449,450: stats (mu, rstd).
__global__ __launch_bounds__(256, 2) void k_gram(const short* __restrict__ XTa,
                                                 const short* __restrict__ XTb,
                                                 const short* __restrict__ MT,
                                                 const int* __restrict__ labels,
                                                 const float* __restrict__ cps,
                                                 const float* __restrict__ cpq,
                                                 float* __restrict__ part,
                                                 float* __restrict__ mu_a,
                                                 float* __restrict__ mu_b,
                                                 float* __restrict__ rs_a,
                                                 float* __restrict__ rs_b,
                                                 int* __restrict__ counts,
                                                 float* __restrict__ out) {
    int bid = blockIdx.x;
    int t = threadIdx.x;

    if (bid >= 448) {
        if (bid == 448) {   // histogram + zero out
            __shared__ int h[NC];
            if (t < NC) h[t] = 0;
            __syncthreads();
            for (int i = t; i < NN; i += 256) atomicAdd(&h[labels[i]], 1);
            __syncthreads();
            if (t < NC) counts[t] = h[t];
            if (t == 0) out[0] = 0.f;
        } else {            // stats for mat = bid-449
            int mat = bid - 449;
            for (int k = t; k < DD; k += 256) {
                int cg = k >> 6, cl = k & 63;
                size_t base = ((size_t)(mat * 8 + cg) * 128) * 64 + cl;
                float s = 0.f, sq = 0.f;
                for (int kg = 0; kg < 128; kg++) {
                    s  += cps[base + (size_t)kg * 64];
                    sq += cpq[base + (size_t)kg * 64];
                }
                float mu = s / (float)NN;
                float var = (sq - (float)NN * mu * mu) / (float)(NN - 1);
                (mat ? mu_b : mu_a)[k] = mu;
                (mat ? rs_b : rs_a)[k] = rsqrtf(var);
            }
        }
        return;
    }

    __shared__ short LA[128 * 64];
    __shared__ short LB[128 * 64];

    int mat = bid / (NTILE * SPLITK);
    int r = bid % (NTILE * SPLITK);
    int chunk = r / NTILE;
    int tile = r % NTILE;
    const short* XT = mat ? XTb : XTa;
    int ti = c_ti[tile], tj = c_tj[tile];
    const short* PA = XT + (size_t)ti * 128 * NN;
    const short* PB = (tj < 4) ? (XT + (size_t)tj * 128 * NN) : MT;
    int k0 = chunk * (NN / SPLITK);

    int wave = t >> 6, lane = t & 63;
    int quad = lane >> 4, l16 = lane & 15;
    int x7 = l16 & 7;
    int wrow = (wave >> 1) * 64, wcol = (wave & 1) * 64;

    int srow = lane >> 3;                 // row within 8-row segment
    int sc = (lane & 7) ^ srow;           // swizzled 16B-chunk index

    f32x4 acc[4][4];
    #pragma unroll
    for (int i = 0; i < 4; i++)
        #pragma unroll
        for (int j = 0; j < 4; j++) acc[i][j] = (f32x4)0.f;

    for (int kk = 0; kk < NN / SPLITK; kk += 64) {
        __syncthreads();
        #pragma unroll
        for (int rr = 0; rr < 4; rr++) {
            int seg = wave * 4 + rr;
            int row = seg * 8 + srow;
            const short* ga = PA + (size_t)row * NN + k0 + kk + sc * 8;
            const short* gb = PB + (size_t)row * NN + k0 + kk + sc * 8;
#ifdef HAVE_GLL
            async16(ga, &LA[seg * 512]);
            async16(gb, &LB[seg * 512]);
#else
            uint4 va = *(const uint4*)ga;
            uint4 vb = *(const uint4*)gb;
            *(uint4*)&LA[seg * 512 + lane * 8] = va;
            *(uint4*)&LB[seg * 512 + lane * 8] = vb;
#endif
        }
        __syncthreads();
        #pragma unroll
        for (int ks = 0; ks < 2; ks++) {
            short8 a[4], b[4];
            #pragma unroll
            for (int mt = 0; mt < 4; mt++)
                a[mt] = *(const short8*)&LA[(wrow + mt * 16 + l16) * 64 +
                                            (((ks * 4 + quad) ^ x7) << 3)];
            #pragma unroll
            for (int nt = 0; nt < 4; nt++)
                b[nt] = *(const short8*)&LB[(wcol + nt * 16 + l16) * 64 +
                                            (((ks * 4 + quad) ^ x7) << 3)];
            #pragma unroll
            for (int mt = 0; mt < 4; mt++)
                #pragma unroll
                for (int nt = 0; nt < 4; nt++)
                    acc[mt][nt] = __builtin_amdgcn_mfma_f32_16x16x32_bf16(
                        a[mt], b[nt], acc[mt][nt], 0, 0, 0);
        }
    }

    float* pbase = part + ((size_t)(mat * NTILE + tile) * SPLITK + chunk) * 16384;
    #pragma unroll
    for (int mt = 0; mt < 4; mt++)
        #pragma unroll
        for (int nt = 0; nt < 4; nt++)
            #pragma unroll
            for (int rj = 0; rj < 4; rj++) {
                int rr2 = wrow + mt * 16 + quad * 4 + rj;
                int cc2 = wcol + nt * 16 + l16;
                pbase[rr2 * 128 + cc2] = acc[mt][nt][rj];
            }
}

// L3: fold SPLITK partials -> Ga/Gb (XX tiles) and RT[class][col] (XM tiles).
__global__ void k_gsum(const float* __restrict__ part,
                       float* __restrict__ Ga, float* __restrict__ Gb,
                       float* __restrict__ RTa, float* __restrict__ RTb) {
    int bid = blockIdx.x;                  // 2*14*64 = 1792
    int mat = bid / (NTILE * 64);
    int rr = bid % (NTILE * 64);
    int tile = rr / 64;
    int e = (rr % 64) * 256 + threadIdx.x;
    const float* p = part + (size_t)(mat * NTILE + tile) * SPLITK * 16384 + e;
    float s = 0.f;
    #pragma unroll
    for (int c = 0; c < SPLITK; c++) s += p[(size_t)c * 16384];
    int rw = e >> 7, cl = e & 127;
    if (tile < NXT) {
        float* G = mat ? Gb : Ga;
        G[(c_ti[tile] * 128 + rw) * DD + c_tj[tile] * 128 + cl] = s;
    } else {
        float* RT = mat ? RTb : RTa;
        RT[cl * DD + (tile - NXT) * 128 + rw] = s;   // [class][col]
    }
}

// L4: blocks 0..255: term1 (upper, diag w=1 off-diag w=2);
//     blocks 256..355: term2 per class; block 256 adds term3.
__global__ void k_term(const float* __restrict__ Ga, const float* __restrict__ Gb,
                       const float* __restrict__ RTa, const float* __restrict__ RTb,
                       const float* __restrict__ mu_a, const float* __restrict__ mu_b,
                       const float* __restrict__ rs_a, const float* __restrict__ rs_b,
                       const int* __restrict__ counts, float* out) {
    int bid = blockIdx.x;
    int t = threadIdx.x;
    if (bid < 256) {
        float local = 0.f;
        for (int x = bid * 256 + t; x < DD * DD; x += 256 * 256) {
            int k = x >> 9, l = x & (DD - 1);
            if (l < k) continue;
            float w = (l == k) ? 1.f : 2.f;
            float ga = rs_a[k] * rs_a[l] * (Ga[x] - (float)NN * mu_a[k] * mu_a[l]);
            float gb = rs_b[k] * rs_b[l] * (Gb[x] - (float)NN * mu_b[k] * mu_b[l]);
            local += w * ga * gb;
        }
        float s = block_reduce_sum(local);
        if (t == 0) atomicAdd(out, s * (1.0f / ((float)DD * (float)DD)));
    } else {
        int c = bid - 256;
        float n = (float)counts[c];
        float local = 0.f;
        for (int k = t; k < DD; k += 256) {
            float ta = rs_a[k] * (RTa[c * DD + k] - n * mu_a[k]);
            float tb = rs_b[k] * (RTb[c * DD + k] - n * mu_b[k]);
            local += ta * tb;
        }
        float s = block_reduce_sum(local);
        if (t == 0) {
            float add = s * (-2.0f / (float)DD);
            if (c == 0) {
                float t3 = 0.f;
                for (int cc = 0; cc < NC; cc++) {
                    float nc = (float)counts[cc];
                    t3 += nc * nc;
                }
                add += t3;
            }
            atomicAdd(out, add);
        }
    }
}

extern "C" void kernel_launch(void* const* d_in, const int* in_sizes, int n_in,
                              void* d_out, int out_size, void* d_ws, size_t ws_size,
                              hipStream_t stream) {
    const float* z_a = (const float*)d_in[0];
    const float* z_b = (const float*)d_in[1];
    const int* labels = (const int*)d_in[2];
    float* out = (float*)d_out;
    char* wsb = (char*)d_ws;

    float* Ga = (float*)(wsb + GA_B);
    float* Gb = (float*)(wsb + GB_B);
    float* RTa = (float*)(wsb + RTA_B);
    float* RTb = (float*)(wsb + RTB_B);
    float* mu_a = (float*)(wsb + MUA_B);
    float* mu_b = (float*)(wsb + MUB_B);
    float* rs_a = (float*)(wsb + RSA_B);
    float* rs_b = (float*)(wsb + RSB_B);
    int* counts = (int*)(wsb + CNT_B);
    float* cps = (float*)(wsb + CPS_B);
    float* cpq = (float*)(wsb + CPQ_B);
    short* XTa = (short*)(wsb + XTA_B);
    short* XTb = (short*)(wsb + XTB_B);
    short* MT = (short*)(wsb + MT_B);
    float* part = (float*)(wsb + PART_B);

    hipLaunchKernelGGL(k_convT, dim3(2176), dim3(256), 0, stream,
                       z_a, z_b, labels, XTa, XTb, MT, cps, cpq);
    hipLaunchKernelGGL(k_gram, dim3(451), dim3(256), 0, stream,
                       XTa, XTb, MT, labels, cps, cpq, part,
                       mu_a, mu_b, rs_a, rs_b, counts, out);
    hipLaunchKernelGGL(k_gsum, dim3(2 * NTILE * 64), dim3(256), 0, stream,
                       part, Ga, Gb, RTa, RTb);
    hipLaunchKernelGGL(k_term, dim3(356), dim3(256), 0, stream,
                       Ga, Gb, RTa, RTb, mu_a, mu_b, rs_a, rs_b, counts, out);
}